// Round 14
// baseline (202.672 us; speedup 1.0000x reference)
//
#include <hip/hip_runtime.h>
#include <hip/hip_bf16.h>

#define B_  32
#define HW_ 4096
#define C_  256
#define S_LDS 40   // LDS row stride in ushorts (80B)

using bf16x8 = __attribute__((ext_vector_type(8))) short;
using f32x4  = __attribute__((ext_vector_type(4))) float;
using u32x4  = __attribute__((ext_vector_type(4))) uint;

__device__ __forceinline__ ushort f2bf_rn(float x) {
    uint u = __builtin_bit_cast(uint, x);
    u += 0x7FFFu + ((u >> 16) & 1u);
    return (ushort)(u >> 16);
}
__device__ __forceinline__ uint pk_bf2(float a, float b) {   // RN pack (K2 only)
    return ((uint)f2bf_rn(b) << 16) | (uint)f2bf_rn(a);
}
// 1-instr RTZ pack of two floats' top-16 bits: {bf16_rtz(x1), bf16_rtz(x0)}
__device__ __forceinline__ uint pk_rtz(float x0, float x1) {
    return __builtin_amdgcn_perm(__builtin_bit_cast(uint, x1),
                                 __builtin_bit_cast(uint, x0), 0x07060302u);
}
// RTZ split: x = hi + lo, hi = truncate-to-bf16, |lo| <= 2^-8|x|
__device__ __forceinline__ void split2_rtz(float x0, float x1, uint& hi2, uint& lo2) {
    uint u0 = __builtin_bit_cast(uint, x0), u1 = __builtin_bit_cast(uint, x1);
    hi2 = __builtin_amdgcn_perm(u1, u0, 0x07060302u);
    float h0 = __builtin_bit_cast(float, u0 & 0xFFFF0000u);
    float h1 = __builtin_bit_cast(float, u1 & 0xFFFF0000u);
    lo2 = pk_rtz(x0 - h0, x1 - h1);
}

// ---------------------------------------------------------------------------
// K1: scores[b,q,k] = sum_hw Q[b,hw,q]*K[b,hw,k] via 3-term bf16 RTZ split
// (proven, absmax 0.0625). R13 winner + BW push:
//  - float2 global loads along channel (wave covers the full 512B Q tile row
//    per instruction; 12 loads/thread/iter instead of 24)
//  - depth-2 register prefetch, 3 rotating buffers (statically unrolled x3),
//    2 iterations of latency cover per load set
//  - collaborative grid order: the 8 (tm,tn) blocks sharing one (b,s)
//    hw-window are consecutive blockIdx -> co-scheduled, rows fully consumed
// Partial-slab epilogue (no atomics). Tile 128q x 64k, sK=4, 2-barrier step.
// grid 1024: x = ((b*4+s)<<3) | (tm*4+tn); block 256 (4 waves, 2x2 of 64x32).
// ---------------------------------------------------------------------------
__global__ __launch_bounds__(256, 3) void scores_kernel(const float* __restrict__ qg,
                                                        const float* __restrict__ kg,
                                                        float* __restrict__ dst,
                                                        long slabStride) {
    int x  = blockIdx.x;
    int tn = x & 3;
    int tm = (x >> 2) & 1;
    int s  = (x >> 3) & 3;
    int b  = x >> 5;

    __shared__ __align__(16) ushort Qhi[128 * S_LDS], Qlo[128 * S_LDS];
    __shared__ __align__(16) ushort Khi[64 * S_LDS],  Klo[64 * S_LDS];

    int tid = threadIdx.x, lane = tid & 63, w = tid >> 6;
    int m0 = (w >> 1) * 64;     // wave q-offset (2x2 wave grid over 128x64)
    int n0 = (w & 1) * 32;      // wave k-offset
    int g = lane >> 4, r16 = lane & 15;

    int qpair = tid & 63;          // Q channel pair (2 ch), lanes contiguous
    int hb    = (tid >> 6) * 8;    // Q hw offset {0,8,16,24}, 8 rows/thread
    int kpair = tid & 31;          // K channel pair
    int hk    = (tid >> 5) * 4;    // K hw offset {0..28}, 4 rows/thread

    const float2* qbase2 = (const float2*)qg + (size_t)b * HW_ * 128 + tm * 64 + qpair;
    const float2* kbase2 = (const float2*)kg + (size_t)b * HW_ * 128 + tn * 32 + kpair;

    f32x4 acc[4][2];
#pragma unroll
    for (int i = 0; i < 4; ++i)
#pragma unroll
        for (int j = 0; j < 2; ++j) acc[i][j] = (f32x4){0.f, 0.f, 0.f, 0.f};

#define LOADQK(qr, kr, itv) {                                                  \
        int hw0 = s * 1024 + (itv) * 32;                                       \
        const float2* qp = qbase2 + (size_t)(hw0 + hb) * 128;                  \
        _Pragma("unroll")                                                      \
        for (int j = 0; j < 8; ++j) qr[j] = qp[(size_t)j * 128];               \
        const float2* kp = kbase2 + (size_t)(hw0 + hk) * 128;                  \
        _Pragma("unroll")                                                      \
        for (int j = 0; j < 4; ++j) kr[j] = kp[(size_t)j * 128];               \
    }

#define CONVERT_STORE(qr, kr) {                                                \
        uint h_[4], l_[4];                                                     \
        split2_rtz(qr[0].x, qr[1].x, h_[0], l_[0]);                            \
        split2_rtz(qr[2].x, qr[3].x, h_[1], l_[1]);                            \
        split2_rtz(qr[4].x, qr[5].x, h_[2], l_[2]);                            \
        split2_rtz(qr[6].x, qr[7].x, h_[3], l_[3]);                            \
        int r0 = (2 * qpair) * S_LDS + hb;                                     \
        *reinterpret_cast<u32x4*>(&Qhi[r0]) = (u32x4){h_[0], h_[1], h_[2], h_[3]}; \
        *reinterpret_cast<u32x4*>(&Qlo[r0]) = (u32x4){l_[0], l_[1], l_[2], l_[3]}; \
        split2_rtz(qr[0].y, qr[1].y, h_[0], l_[0]);                            \
        split2_rtz(qr[2].y, qr[3].y, h_[1], l_[1]);                            \
        split2_rtz(qr[4].y, qr[5].y, h_[2], l_[2]);                            \
        split2_rtz(qr[6].y, qr[7].y, h_[3], l_[3]);                            \
        int r1 = (2 * qpair + 1) * S_LDS + hb;                                 \
        *reinterpret_cast<u32x4*>(&Qhi[r1]) = (u32x4){h_[0], h_[1], h_[2], h_[3]}; \
        *reinterpret_cast<u32x4*>(&Qlo[r1]) = (u32x4){l_[0], l_[1], l_[2], l_[3]}; \
        uint ha, hb2, la, lb;                                                  \
        split2_rtz(kr[0].x, kr[1].x, ha, la);                                  \
        split2_rtz(kr[2].x, kr[3].x, hb2, lb);                                 \
        int rk0 = (2 * kpair) * S_LDS + hk;                                    \
        *reinterpret_cast<uint2*>(&Khi[rk0]) = make_uint2(ha, hb2);            \
        *reinterpret_cast<uint2*>(&Klo[rk0]) = make_uint2(la, lb);             \
        split2_rtz(kr[0].y, kr[1].y, ha, la);                                  \
        split2_rtz(kr[2].y, kr[3].y, hb2, lb);                                 \
        int rk1 = (2 * kpair + 1) * S_LDS + hk;                                \
        *reinterpret_cast<uint2*>(&Khi[rk1]) = make_uint2(ha, hb2);            \
        *reinterpret_cast<uint2*>(&Klo[rk1]) = make_uint2(la, lb);             \
    }

#define MFMA_PHASE() {                                                         \
        __builtin_amdgcn_s_setprio(1);                                         \
        bf16x8 ahi[4], alo[4];                                                 \
        _Pragma("unroll")                                                      \
        for (int mi = 0; mi < 4; ++mi) {                                       \
            int off = (m0 + mi * 16 + r16) * S_LDS + g * 8;                    \
            ahi[mi] = *reinterpret_cast<const bf16x8*>(&Qhi[off]);             \
            alo[mi] = *reinterpret_cast<const bf16x8*>(&Qlo[off]);             \
        }                                                                      \
        _Pragma("unroll")                                                      \
        for (int ni = 0; ni < 2; ++ni) {                                       \
            int off = (n0 + ni * 16 + r16) * S_LDS + g * 8;                    \
            bf16x8 bhi = *reinterpret_cast<const bf16x8*>(&Khi[off]);          \
            bf16x8 blo = *reinterpret_cast<const bf16x8*>(&Klo[off]);          \
            _Pragma("unroll")                                                  \
            for (int mi = 0; mi < 4; ++mi) {                                   \
                acc[mi][ni] = __builtin_amdgcn_mfma_f32_16x16x32_bf16(ahi[mi], bhi, acc[mi][ni], 0, 0, 0); \
                acc[mi][ni] = __builtin_amdgcn_mfma_f32_16x16x32_bf16(ahi[mi], blo, acc[mi][ni], 0, 0, 0); \
                acc[mi][ni] = __builtin_amdgcn_mfma_f32_16x16x32_bf16(alo[mi], bhi, acc[mi][ni], 0, 0, 0); \
            }                                                                  \
        }                                                                      \
        __builtin_amdgcn_s_setprio(0);                                         \
    }

#define STEP(qc, kc, qn, kn, itv, doload) {                                    \
        if (doload) LOADQK(qn, kn, (itv) + 2);                                 \
        __syncthreads();                                                       \
        CONVERT_STORE(qc, kc);                                                 \
        __syncthreads();                                                       \
        MFMA_PHASE();                                                          \
    }

    float2 qA[8], qB[8], qC[8], kA[4], kB[4], kC[4];
    LOADQK(qA, kA, 0);
    LOADQK(qB, kB, 1);
    for (int p = 0; p < 10; ++p) {
        STEP(qA, kA, qC, kC, 3 * p,     true);   // uses A, loads iter 3p+2 -> C
        STEP(qB, kB, qA, kA, 3 * p + 1, true);   // uses B, loads iter 3p+3 -> A
        STEP(qC, kC, qB, kB, 3 * p + 2, true);   // uses C, loads iter 3p+4 -> B
    }
    STEP(qA, kA, qC, kC, 30, false);   // drain
    STEP(qB, kB, qC, kC, 31, false);

    // epilogue: C/D layout col=lane&15, row=(lane>>4)*4+reg (m89-verified)
    float* base = dst + (size_t)s * slabStride;
#pragma unroll
    for (int mi = 0; mi < 4; ++mi)
#pragma unroll
        for (int ni = 0; ni < 2; ++ni)
#pragma unroll
            for (int r = 0; r < 4; ++r) {
                int qrow = tm * 128 + m0 + mi * 16 + g * 4 + r;
                int kc   = tn * 64 + n0 + ni * 16 + r16;
                float* p = base + ((size_t)b * 256 + qrow) * 256 + kc;
                if (slabStride) *p = acc[mi][ni][r];
                else            atomicAdd(p, acc[mi][ni][r]);
            }
#undef STEP
#undef MFMA_PHASE
#undef CONVERT_STORE
#undef LOADQK
}

// ---------------------------------------------------------------------------
// K2: sum nslab partial slabs, then row softmax over k (256); one wave/row.
// ---------------------------------------------------------------------------
__global__ __launch_bounds__(256) void softmax_kernel(const float* __restrict__ scores,
                                                      ushort* __restrict__ attn,
                                                      int nslab, long slabStride) {
    int wid  = blockIdx.x * 4 + (threadIdx.x >> 6);
    int lane = threadIdx.x & 63;
    const float* p0 = scores + (size_t)wid * 256 + lane * 4;
    float4 v = *reinterpret_cast<const float4*>(p0);
    for (int sl = 1; sl < nslab; ++sl) {
        const float4 t = *reinterpret_cast<const float4*>(p0 + (size_t)sl * slabStride);
        v.x += t.x; v.y += t.y; v.z += t.z; v.w += t.w;
    }
    float m = fmaxf(fmaxf(v.x, v.y), fmaxf(v.z, v.w));
#pragma unroll
    for (int off = 32; off; off >>= 1) m = fmaxf(m, __shfl_xor(m, off, 64));
    float e0 = __expf(v.x - m), e1 = __expf(v.y - m), e2 = __expf(v.z - m), e3 = __expf(v.w - m);
    float ssum = e0 + e1 + e2 + e3;
#pragma unroll
    for (int off = 32; off; off >>= 1) ssum += __shfl_xor(ssum, off, 64);
    float inv = 1.0f / ssum;
    uint2 o;
    o.x = pk_bf2(e0 * inv, e1 * inv);
    o.y = pk_bf2(e2 * inv, e3 * inv);
    *reinterpret_cast<uint2*>(attn + (size_t)wid * 256 + lane * 4) = o;
}

// ---------------------------------------------------------------------------
// K3: out[b,q,hw] = sum_k attn[b,q,k] * V[b,hw,k].  M=256 x N=64 tile, K=256
// in 8 steps of 32. V tile staged ONCE per block into LDS (fp32, XOR-swizzled
// 16B slots), double-buffered with T14 async-stage. (5x validated, 0.0625;
// at its ~41us traffic floor)
// grid 2048 = b(32) * hw-tile(64); block 256 (4 waves, each 64q x 64hw).
// ---------------------------------------------------------------------------
__global__ __launch_bounds__(256, 4) void pv_kernel(const ushort* __restrict__ attn,
                                                    const float* __restrict__ vg,
                                                    float* __restrict__ out) {
    int b   = blockIdx.x >> 6;
    int hw0 = (blockIdx.x & 63) * 64;
    int tid = threadIdx.x, lane = tid & 63, w = tid >> 6;
    int m0  = w * 64;
    int g   = lane >> 4, r16 = lane & 15;

    __shared__ __align__(16) float Vt[2 * 64 * 32];   // [buf][hw 64][k 32], swizzled

    int srow = tid >> 2;
    int sslot = (tid & 3) * 2;
    int wi0 = srow * 32 + ((sslot ^ (srow & 7)) * 4);
    int wi1 = srow * 32 + (((sslot + 1) ^ (srow & 7)) * 4);
    const float* vstage = vg + ((size_t)(b * HW_ + hw0 + srow)) * C_ + sslot * 4;

    const ushort* abase = attn + (size_t)b * 256 * 256 + g * 8;

    f32x4 acc[4][4];
#pragma unroll
    for (int i = 0; i < 4; ++i)
#pragma unroll
        for (int j = 0; j < 4; ++j) acc[i][j] = (f32x4){0.f, 0.f, 0.f, 0.f};

    {
        f32x4 p0 = *reinterpret_cast<const f32x4*>(vstage);
        f32x4 p1 = *reinterpret_cast<const f32x4*>(vstage + 4);
        *reinterpret_cast<f32x4*>(&Vt[wi0]) = p0;
        *reinterpret_cast<f32x4*>(&Vt[wi1]) = p1;
    }
    __syncthreads();

    for (int p = 0; p < 8; ++p) {
        float* rbuf = &Vt[(p & 1) * 64 * 32];
        float* wbuf = &Vt[((p + 1) & 1) * 64 * 32];

        f32x4 n0v, n1v;
        if (p < 7) {
            n0v = *reinterpret_cast<const f32x4*>(vstage + (p + 1) * 32);
            n1v = *reinterpret_cast<const f32x4*>(vstage + (p + 1) * 32 + 4);
        }

        int k0 = p * 32;
        bf16x8 a[4];
#pragma unroll
        for (int mi = 0; mi < 4; ++mi)
            a[mi] = *reinterpret_cast<const bf16x8*>(abase + (size_t)(m0 + mi * 16 + r16) * 256 + k0);

#pragma unroll
        for (int ni = 0; ni < 4; ++ni) {
            int row = ni * 16 + r16, key = row & 7;
            f32x4 f0 = *reinterpret_cast<const f32x4*>(&rbuf[row * 32 + (((2 * g)     ^ key) * 4)]);
            f32x4 f1 = *reinterpret_cast<const f32x4*>(&rbuf[row * 32 + (((2 * g + 1) ^ key) * 4)]);
            bf16x8 bf = __builtin_bit_cast(bf16x8, (u32x4){
                pk_rtz(f0[0], f0[1]), pk_rtz(f0[2], f0[3]),
                pk_rtz(f1[0], f1[1]), pk_rtz(f1[2], f1[3])});
#pragma unroll
            for (int mi = 0; mi < 4; ++mi)
                acc[mi][ni] = __builtin_amdgcn_mfma_f32_16x16x32_bf16(a[mi], bf, acc[mi][ni], 0, 0, 0);
        }

        if (p < 7) {
            *reinterpret_cast<f32x4*>(&wbuf[wi0]) = n0v;
            *reinterpret_cast<f32x4*>(&wbuf[wi1]) = n1v;
            __syncthreads();
        }
    }

#pragma unroll
    for (int mi = 0; mi < 4; ++mi)
#pragma unroll
        for (int ni = 0; ni < 4; ++ni)
#pragma unroll
            for (int r = 0; r < 4; ++r) {
                int qrow = m0 + mi * 16 + g * 4 + r;
                int hw   = hw0 + ni * 16 + r16;
                out[((size_t)b * 256 + qrow) * 4096 + hw] = acc[mi][ni][r];
            }
}

extern "C" void kernel_launch(void* const* d_in, const int* in_sizes, int n_in,
                              void* d_out, int out_size, void* d_ws, size_t ws_size,
                              hipStream_t stream) {
    const float* q = (const float*)d_in[0];
    const float* k = (const float*)d_in[1];
    const float* v = (const float*)d_in[2];
    float* out = (float*)d_out;

    const size_t slab = (size_t)B_ * 256 * 256;          // floats per slab (8 MB)
    const size_t needBytes = 4 * slab * 4 + slab * 2;    // 4 slabs + bf16 attn = 36 MB
    float* scores = (float*)d_ws;

    if (ws_size >= needBytes) {
        // partials path: no atomics, no memset
        ushort* attn = (ushort*)((char*)d_ws + 4 * slab * 4);
        scores_kernel<<<1024, 256, 0, stream>>>(q, k, scores, (long)slab);
        softmax_kernel<<<2048, 256, 0, stream>>>(scores, attn, 4, (long)slab);
        pv_kernel<<<2048, 256, 0, stream>>>(attn, v, out);
    } else {
        // atomic fallback (proven path)
        ushort* attn = (ushort*)((char*)d_ws + slab * 4);
        (void)hipMemsetAsync(d_ws, 0, slab * 4, stream);
        scores_kernel<<<1024, 256, 0, stream>>>(q, k, scores, 0L);
        softmax_kernel<<<2048, 256, 0, stream>>>(scores, attn, 1, 0L);
        pv_kernel<<<2048, 256, 0, stream>>>(attn, v, out);
    }
}

// Round 15
// 189.265 us; speedup vs baseline: 1.0708x; 1.0708x over previous
//
#include <hip/hip_runtime.h>
#include <hip/hip_bf16.h>

#define B_  32
#define HW_ 4096
#define C_  256
#define S_LDS 40   // LDS row stride in ushorts (80B)

using bf16x8 = __attribute__((ext_vector_type(8))) short;
using f32x4  = __attribute__((ext_vector_type(4))) float;
using u32x4  = __attribute__((ext_vector_type(4))) uint;

__device__ __forceinline__ ushort f2bf_rn(float x) {
    uint u = __builtin_bit_cast(uint, x);
    u += 0x7FFFu + ((u >> 16) & 1u);
    return (ushort)(u >> 16);
}
__device__ __forceinline__ uint pk_bf2(float a, float b) {   // RN pack (K2 only)
    return ((uint)f2bf_rn(b) << 16) | (uint)f2bf_rn(a);
}
// 1-instr RTZ pack of two floats' top-16 bits: {bf16_rtz(x1), bf16_rtz(x0)}
__device__ __forceinline__ uint pk_rtz(float x0, float x1) {
    return __builtin_amdgcn_perm(__builtin_bit_cast(uint, x1),
                                 __builtin_bit_cast(uint, x0), 0x07060302u);
}
// RTZ split: x = hi + lo, hi = truncate-to-bf16, |lo| <= 2^-8|x|
__device__ __forceinline__ void split2_rtz(float x0, float x1, uint& hi2, uint& lo2) {
    uint u0 = __builtin_bit_cast(uint, x0), u1 = __builtin_bit_cast(uint, x1);
    hi2 = __builtin_amdgcn_perm(u1, u0, 0x07060302u);
    float h0 = __builtin_bit_cast(float, u0 & 0xFFFF0000u);
    float h1 = __builtin_bit_cast(float, u1 & 0xFFFF0000u);
    lo2 = pk_rtz(x0 - h0, x1 - h1);
}

// ---------------------------------------------------------------------------
// K1: scores[b,q,k] = sum_hw Q[b,hw,q]*K[b,hw,k] via 3-term bf16 RTZ split
// (proven, absmax 0.0625). float2 loads + depth-2 prefetch (R14 pipeline,
// proved 3.2 TB/s sustainable) with R14's two regressions fixed:
//  - grid order back to R13's (s in low bits): data-sharing blocks land on
//    few XCDs -> L2-dedup, FETCH ~230MB (R14's order: 8 XCDs, 393MB)
//  - LDS row permutation lrow(c) = (c>>1) + (c&1)*(ROWS/2): a thread's
//    channel pair (2q,2q+1) -> rows q, q+64 => store instructions hit 64
//    CONSECUTIVE rows (~2-way banks, free) instead of even-row 16-way.
// Partial-slab epilogue (no atomics). Tile 128q x 64k, sK=4, 2-barrier step.
// grid 1024 = b(32) * tm(2) * tn(4) * s(4); block 256 (4 waves, 2x2 of 64x32).
// ---------------------------------------------------------------------------
__global__ __launch_bounds__(256, 3) void scores_kernel(const float* __restrict__ qg,
                                                        const float* __restrict__ kg,
                                                        float* __restrict__ dst,
                                                        long slabStride) {
    int x  = blockIdx.x;
    int s  = x & 3;
    int tn = (x >> 2) & 3;
    int tm = (x >> 4) & 1;
    int b  = x >> 5;

    __shared__ __align__(16) ushort Qhi[128 * S_LDS], Qlo[128 * S_LDS];
    __shared__ __align__(16) ushort Khi[64 * S_LDS],  Klo[64 * S_LDS];

    int tid = threadIdx.x, lane = tid & 63, w = tid >> 6;
    int m0 = (w >> 1) * 64;     // wave q-offset (2x2 wave grid over 128x64)
    int n0 = (w & 1) * 32;      // wave k-offset
    int g = lane >> 4, r16 = lane & 15;

    int qpair = tid & 63;          // Q channel pair (2ch) owned by thread
    int hb    = (tid >> 6) * 8;    // Q hw offset {0,8,16,24}, 8 rows/thread
    int kpair = tid & 31;          // K channel pair
    int hk    = (tid >> 5) * 4;    // K hw offset, 4 rows/thread

    const float2* qbase2 = (const float2*)qg + (size_t)b * HW_ * 128 + tm * 64 + qpair;
    const float2* kbase2 = (const float2*)kg + (size_t)b * HW_ * 128 + tn * 32 + kpair;

    f32x4 acc[4][2];
#pragma unroll
    for (int i = 0; i < 4; ++i)
#pragma unroll
        for (int j = 0; j < 2; ++j) acc[i][j] = (f32x4){0.f, 0.f, 0.f, 0.f};

#define LOADQK(qr, kr, itv) {                                                  \
        int hw0 = s * 1024 + (itv) * 32;                                       \
        const float2* qp = qbase2 + (size_t)(hw0 + hb) * 128;                  \
        _Pragma("unroll")                                                      \
        for (int j = 0; j < 8; ++j) qr[j] = qp[(size_t)j * 128];               \
        const float2* kp = kbase2 + (size_t)(hw0 + hk) * 128;                  \
        _Pragma("unroll")                                                      \
        for (int j = 0; j < 4; ++j) kr[j] = kp[(size_t)j * 128];               \
    }

// channel 2*qpair -> lrow qpair; channel 2*qpair+1 -> lrow qpair+64 (Q)
// channel 2*kpair -> lrow kpair; channel 2*kpair+1 -> lrow kpair+32 (K)
#define CONVERT_STORE(qr, kr) {                                                \
        uint h_[4], l_[4];                                                     \
        split2_rtz(qr[0].x, qr[1].x, h_[0], l_[0]);                            \
        split2_rtz(qr[2].x, qr[3].x, h_[1], l_[1]);                            \
        split2_rtz(qr[4].x, qr[5].x, h_[2], l_[2]);                            \
        split2_rtz(qr[6].x, qr[7].x, h_[3], l_[3]);                            \
        int r0 = qpair * S_LDS + hb;                                           \
        *reinterpret_cast<u32x4*>(&Qhi[r0]) = (u32x4){h_[0], h_[1], h_[2], h_[3]}; \
        *reinterpret_cast<u32x4*>(&Qlo[r0]) = (u32x4){l_[0], l_[1], l_[2], l_[3]}; \
        split2_rtz(qr[0].y, qr[1].y, h_[0], l_[0]);                            \
        split2_rtz(qr[2].y, qr[3].y, h_[1], l_[1]);                            \
        split2_rtz(qr[4].y, qr[5].y, h_[2], l_[2]);                            \
        split2_rtz(qr[6].y, qr[7].y, h_[3], l_[3]);                            \
        int r1 = (qpair + 64) * S_LDS + hb;                                    \
        *reinterpret_cast<u32x4*>(&Qhi[r1]) = (u32x4){h_[0], h_[1], h_[2], h_[3]}; \
        *reinterpret_cast<u32x4*>(&Qlo[r1]) = (u32x4){l_[0], l_[1], l_[2], l_[3]}; \
        uint ha, hb2, la, lb;                                                  \
        split2_rtz(kr[0].x, kr[1].x, ha, la);                                  \
        split2_rtz(kr[2].x, kr[3].x, hb2, lb);                                 \
        int rk0 = kpair * S_LDS + hk;                                          \
        *reinterpret_cast<uint2*>(&Khi[rk0]) = make_uint2(ha, hb2);            \
        *reinterpret_cast<uint2*>(&Klo[rk0]) = make_uint2(la, lb);             \
        split2_rtz(kr[0].y, kr[1].y, ha, la);                                  \
        split2_rtz(kr[2].y, kr[3].y, hb2, lb);                                 \
        int rk1 = (kpair + 32) * S_LDS + hk;                                   \
        *reinterpret_cast<uint2*>(&Khi[rk1]) = make_uint2(ha, hb2);            \
        *reinterpret_cast<uint2*>(&Klo[rk1]) = make_uint2(la, lb);             \
    }

#define MFMA_PHASE() {                                                         \
        __builtin_amdgcn_s_setprio(1);                                         \
        bf16x8 ahi[4], alo[4];                                                 \
        _Pragma("unroll")                                                      \
        for (int mi = 0; mi < 4; ++mi) {                                       \
            int c = m0 + mi * 16 + r16;                                        \
            int off = ((c >> 1) + ((c & 1) << 6)) * S_LDS + g * 8;             \
            ahi[mi] = *reinterpret_cast<const bf16x8*>(&Qhi[off]);             \
            alo[mi] = *reinterpret_cast<const bf16x8*>(&Qlo[off]);             \
        }                                                                      \
        _Pragma("unroll")                                                      \
        for (int ni = 0; ni < 2; ++ni) {                                       \
            int c = n0 + ni * 16 + r16;                                        \
            int off = ((c >> 1) + ((c & 1) << 5)) * S_LDS + g * 8;             \
            bf16x8 bhi = *reinterpret_cast<const bf16x8*>(&Khi[off]);          \
            bf16x8 blo = *reinterpret_cast<const bf16x8*>(&Klo[off]);          \
            _Pragma("unroll")                                                  \
            for (int mi = 0; mi < 4; ++mi) {                                   \
                acc[mi][ni] = __builtin_amdgcn_mfma_f32_16x16x32_bf16(ahi[mi], bhi, acc[mi][ni], 0, 0, 0); \
                acc[mi][ni] = __builtin_amdgcn_mfma_f32_16x16x32_bf16(ahi[mi], blo, acc[mi][ni], 0, 0, 0); \
                acc[mi][ni] = __builtin_amdgcn_mfma_f32_16x16x32_bf16(alo[mi], bhi, acc[mi][ni], 0, 0, 0); \
            }                                                                  \
        }                                                                      \
        __builtin_amdgcn_s_setprio(0);                                         \
    }

#define STEP(qc, kc, qn, kn, itv, doload) {                                    \
        if (doload) LOADQK(qn, kn, (itv) + 2);                                 \
        __syncthreads();                                                       \
        CONVERT_STORE(qc, kc);                                                 \
        __syncthreads();                                                       \
        MFMA_PHASE();                                                          \
    }

    float2 qA[8], qB[8], qC[8], kA[4], kB[4], kC[4];
    LOADQK(qA, kA, 0);
    LOADQK(qB, kB, 1);
    for (int p = 0; p < 10; ++p) {
        STEP(qA, kA, qC, kC, 3 * p,     true);   // uses A, loads iter 3p+2 -> C
        STEP(qB, kB, qA, kA, 3 * p + 1, true);   // uses B, loads iter 3p+3 -> A
        STEP(qC, kC, qB, kB, 3 * p + 2, true);   // uses C, loads iter 3p+4 -> B
    }
    STEP(qA, kA, qC, kC, 30, false);   // drain
    STEP(qB, kB, qC, kC, 31, false);

    // epilogue: C/D layout col=lane&15, row=(lane>>4)*4+reg (m89-verified)
    float* base = dst + (size_t)s * slabStride;
#pragma unroll
    for (int mi = 0; mi < 4; ++mi)
#pragma unroll
        for (int ni = 0; ni < 2; ++ni)
#pragma unroll
            for (int r = 0; r < 4; ++r) {
                int qrow = tm * 128 + m0 + mi * 16 + g * 4 + r;
                int kc   = tn * 64 + n0 + ni * 16 + r16;
                float* p = base + ((size_t)b * 256 + qrow) * 256 + kc;
                if (slabStride) *p = acc[mi][ni][r];
                else            atomicAdd(p, acc[mi][ni][r]);
            }
#undef STEP
#undef MFMA_PHASE
#undef CONVERT_STORE
#undef LOADQK
}

// ---------------------------------------------------------------------------
// K2: sum nslab partial slabs, then row softmax over k (256); one wave/row.
// ---------------------------------------------------------------------------
__global__ __launch_bounds__(256) void softmax_kernel(const float* __restrict__ scores,
                                                      ushort* __restrict__ attn,
                                                      int nslab, long slabStride) {
    int wid  = blockIdx.x * 4 + (threadIdx.x >> 6);
    int lane = threadIdx.x & 63;
    const float* p0 = scores + (size_t)wid * 256 + lane * 4;
    float4 v = *reinterpret_cast<const float4*>(p0);
    for (int sl = 1; sl < nslab; ++sl) {
        const float4 t = *reinterpret_cast<const float4*>(p0 + (size_t)sl * slabStride);
        v.x += t.x; v.y += t.y; v.z += t.z; v.w += t.w;
    }
    float m = fmaxf(fmaxf(v.x, v.y), fmaxf(v.z, v.w));
#pragma unroll
    for (int off = 32; off; off >>= 1) m = fmaxf(m, __shfl_xor(m, off, 64));
    float e0 = __expf(v.x - m), e1 = __expf(v.y - m), e2 = __expf(v.z - m), e3 = __expf(v.w - m);
    float ssum = e0 + e1 + e2 + e3;
#pragma unroll
    for (int off = 32; off; off >>= 1) ssum += __shfl_xor(ssum, off, 64);
    float inv = 1.0f / ssum;
    uint2 o;
    o.x = pk_bf2(e0 * inv, e1 * inv);
    o.y = pk_bf2(e2 * inv, e3 * inv);
    *reinterpret_cast<uint2*>(attn + (size_t)wid * 256 + lane * 4) = o;
}

// ---------------------------------------------------------------------------
// K3: out[b,q,hw] = sum_k attn[b,q,k] * V[b,hw,k].  M=256 x N=64 tile, K=256
// in 8 steps of 32. V tile staged ONCE per block into LDS (fp32, XOR-swizzled
// 16B slots), double-buffered with T14 async-stage. (6x validated, 0.0625;
// at its ~41us traffic floor)
// grid 2048 = b(32) * hw-tile(64); block 256 (4 waves, each 64q x 64hw).
// ---------------------------------------------------------------------------
__global__ __launch_bounds__(256, 4) void pv_kernel(const ushort* __restrict__ attn,
                                                    const float* __restrict__ vg,
                                                    float* __restrict__ out) {
    int b   = blockIdx.x >> 6;
    int hw0 = (blockIdx.x & 63) * 64;
    int tid = threadIdx.x, lane = tid & 63, w = tid >> 6;
    int m0  = w * 64;
    int g   = lane >> 4, r16 = lane & 15;

    __shared__ __align__(16) float Vt[2 * 64 * 32];   // [buf][hw 64][k 32], swizzled

    int srow = tid >> 2;
    int sslot = (tid & 3) * 2;
    int wi0 = srow * 32 + ((sslot ^ (srow & 7)) * 4);
    int wi1 = srow * 32 + (((sslot + 1) ^ (srow & 7)) * 4);
    const float* vstage = vg + ((size_t)(b * HW_ + hw0 + srow)) * C_ + sslot * 4;

    const ushort* abase = attn + (size_t)b * 256 * 256 + g * 8;

    f32x4 acc[4][4];
#pragma unroll
    for (int i = 0; i < 4; ++i)
#pragma unroll
        for (int j = 0; j < 4; ++j) acc[i][j] = (f32x4){0.f, 0.f, 0.f, 0.f};

    {
        f32x4 p0 = *reinterpret_cast<const f32x4*>(vstage);
        f32x4 p1 = *reinterpret_cast<const f32x4*>(vstage + 4);
        *reinterpret_cast<f32x4*>(&Vt[wi0]) = p0;
        *reinterpret_cast<f32x4*>(&Vt[wi1]) = p1;
    }
    __syncthreads();

    for (int p = 0; p < 8; ++p) {
        float* rbuf = &Vt[(p & 1) * 64 * 32];
        float* wbuf = &Vt[((p + 1) & 1) * 64 * 32];

        f32x4 n0v, n1v;
        if (p < 7) {
            n0v = *reinterpret_cast<const f32x4*>(vstage + (p + 1) * 32);
            n1v = *reinterpret_cast<const f32x4*>(vstage + (p + 1) * 32 + 4);
        }

        int k0 = p * 32;
        bf16x8 a[4];
#pragma unroll
        for (int mi = 0; mi < 4; ++mi)
            a[mi] = *reinterpret_cast<const bf16x8*>(abase + (size_t)(m0 + mi * 16 + r16) * 256 + k0);

#pragma unroll
        for (int ni = 0; ni < 4; ++ni) {
            int row = ni * 16 + r16, key = row & 7;
            f32x4 f0 = *reinterpret_cast<const f32x4*>(&rbuf[row * 32 + (((2 * g)     ^ key) * 4)]);
            f32x4 f1 = *reinterpret_cast<const f32x4*>(&rbuf[row * 32 + (((2 * g + 1) ^ key) * 4)]);
            bf16x8 bf = __builtin_bit_cast(bf16x8, (u32x4){
                pk_rtz(f0[0], f0[1]), pk_rtz(f0[2], f0[3]),
                pk_rtz(f1[0], f1[1]), pk_rtz(f1[2], f1[3])});
#pragma unroll
            for (int mi = 0; mi < 4; ++mi)
                acc[mi][ni] = __builtin_amdgcn_mfma_f32_16x16x32_bf16(a[mi], bf, acc[mi][ni], 0, 0, 0);
        }

        if (p < 7) {
            *reinterpret_cast<f32x4*>(&wbuf[wi0]) = n0v;
            *reinterpret_cast<f32x4*>(&wbuf[wi1]) = n1v;
            __syncthreads();
        }
    }

#pragma unroll
    for (int mi = 0; mi < 4; ++mi)
#pragma unroll
        for (int ni = 0; ni < 4; ++ni)
#pragma unroll
            for (int r = 0; r < 4; ++r) {
                int qrow = m0 + mi * 16 + g * 4 + r;
                int hw   = hw0 + ni * 16 + r16;
                out[((size_t)b * 256 + qrow) * 4096 + hw] = acc[mi][ni][r];
            }
}

extern "C" void kernel_launch(void* const* d_in, const int* in_sizes, int n_in,
                              void* d_out, int out_size, void* d_ws, size_t ws_size,
                              hipStream_t stream) {
    const float* q = (const float*)d_in[0];
    const float* k = (const float*)d_in[1];
    const float* v = (const float*)d_in[2];
    float* out = (float*)d_out;

    const size_t slab = (size_t)B_ * 256 * 256;          // floats per slab (8 MB)
    const size_t needBytes = 4 * slab * 4 + slab * 2;    // 4 slabs + bf16 attn = 36 MB
    float* scores = (float*)d_ws;

    if (ws_size >= needBytes) {
        // partials path: no atomics, no memset
        ushort* attn = (ushort*)((char*)d_ws + 4 * slab * 4);
        scores_kernel<<<1024, 256, 0, stream>>>(q, k, scores, (long)slab);
        softmax_kernel<<<2048, 256, 0, stream>>>(scores, attn, 4, (long)slab);
        pv_kernel<<<2048, 256, 0, stream>>>(attn, v, out);
    } else {
        // atomic fallback (proven path)
        ushort* attn = (ushort*)((char*)d_ws + slab * 4);
        (void)hipMemsetAsync(d_ws, 0, slab * 4, stream);
        scores_kernel<<<1024, 256, 0, stream>>>(q, k, scores, 0L);
        softmax_kernel<<<2048, 256, 0, stream>>>(scores, attn, 1, 0L);
        pv_kernel<<<2048, 256, 0, stream>>>(attn, v, out);
    }
}